// Round 8
// baseline (255.442 us; speedup 1.0000x reference)
//
#include <hip/hip_runtime.h>
#include <hip/hip_bf16.h>

#define NN 50000
#define NE 1600000
#define ET (NE + NN)   // 1,650,000 incl. self loops
#define H1 8
#define C1 16
#define D1 128
#define C2 16
#define NB1 196        // ceil(NN/256)
#define OCTW 6250      // NN/8 dsts per octant
#define NSL 64         // slices for atomic-free CSR build
#define SLE (NE / NSL) // 25,000 edges per slice

#define HIST_NB 512    // 8 octants x 64 slices
#define PACK_NB 1563   // ceil(NE/4/256)
#define PREP_NB 8      // WextT build, one head per block
#define SCAT_NB 512
#define GEMM_NB 782    // ceil(50000/64)

typedef unsigned short u16;
typedef unsigned int u32;
typedef u32 u32x4 __attribute__((ext_vector_type(4)));
typedef __bf16 bf16x8 __attribute__((ext_vector_type(8)));
typedef float f32x4v __attribute__((ext_vector_type(4)));

// ==================================================================
// K1: fused [slice-hist | pack | prep-WextT]
// ==================================================================
__device__ void hist_role(int hbid, char* smem, const int* __restrict__ ei,
                          u16* __restrict__ hs) {
  int* hl = (int*)smem;                     // OCTW ints = 25000 B
  const int oct = hbid & 7;
  const int s   = hbid >> 3;
  const int lo  = oct * OCTW;
  const int tid = threadIdx.x;
  for (int j = tid; j < OCTW; j += 256) hl[j] = 0;
  __syncthreads();
  const int4* dp = (const int4*)(ei + NE) + (size_t)s * (SLE / 4);
  for (int g = tid; g < SLE / 4; g += 256) {
    int4 v = dp[g];
    int a = v.x - lo, b = v.y - lo, c = v.z - lo, d = v.w - lo;
    if ((unsigned)a < OCTW) atomicAdd(&hl[a], 1);
    if ((unsigned)b < OCTW) atomicAdd(&hl[b], 1);
    if ((unsigned)c < OCTW) atomicAdd(&hl[c], 1);
    if ((unsigned)d < OCTW) atomicAdd(&hl[d], 1);
  }
  __syncthreads();
  u16* out = hs + (size_t)s * NN + lo;
  for (int j = tid; j < OCTW; j += 256) out[j] = (u16)hl[j];
}

__device__ void pack_role(int pbid, const int* __restrict__ ei,
                          u16* __restrict__ src16, u16* __restrict__ dst16) {
  int i = pbid * 256 + threadIdx.x;
  if (i >= NE / 4) return;
  int4 s = ((const int4*)ei)[i];
  int4 d = ((const int4*)(ei + NE))[i];
  ushort4 sp; sp.x = (u16)s.x; sp.y = (u16)s.y; sp.z = (u16)s.z; sp.w = (u16)s.w;
  ushort4 dp; dp.x = (u16)d.x; dp.y = (u16)d.y; dp.z = (u16)d.z; dp.w = (u16)d.w;
  ((ushort4*)src16)[i] = sp;
  ((ushort4*)dst16)[i] = dp;
}

// WextT[144][128] bf16 (col-major Wext): rows 0-127 = W1^T; 128+h = W1@aS_h; 136+h = W1@aD_h
__device__ void prep_role(int pbid, const float* __restrict__ W1,
    const float* __restrict__ aS, const float* __restrict__ aD,
    __hip_bfloat16* __restrict__ WextT) {
  const int k = threadIdx.x;
  if (k >= 128) return;
  const int h = pbid;            // 0..7
#pragma unroll
  for (int j = 0; j < 16; ++j) {
    int n = h * 16 + j;
    WextT[(size_t)n * 128 + k] = __float2bfloat16(W1[(size_t)k * 128 + n]);
  }
  float s = 0.f, dv = 0.f;
#pragma unroll
  for (int c = 0; c < 16; ++c) {
    float w = W1[(size_t)k * 128 + h * 16 + c];
    s  = fmaf(w, aS[h * 16 + c], s);
    dv = fmaf(w, aD[h * 16 + c], dv);
  }
  WextT[(size_t)(128 + h) * 128 + k] = __float2bfloat16(s);
  WextT[(size_t)(136 + h) * 128 + k] = __float2bfloat16(dv);
}

__global__ __launch_bounds__(256) void k1_fused(const int* __restrict__ ei,
    u16* __restrict__ hs, u16* __restrict__ src16, u16* __restrict__ dst16,
    const float* __restrict__ W1, const float* __restrict__ aS,
    const float* __restrict__ aD, __hip_bfloat16* __restrict__ WextT) {
  __shared__ __align__(16) char smem[25088];
  const int bid = blockIdx.x;
  if (bid < HIST_NB) hist_role(bid, smem, ei, hs);
  else if (bid < HIST_NB + PACK_NB) pack_role(bid - HIST_NB, ei, src16, dst16);
  else prep_role(bid - HIST_NB - PACK_NB, W1, aS, aD, WextT);
}

// ==================================================================
// scans; scan1 converts hs to exclusive prefix along slices (in place)
// ==================================================================
__global__ __launch_bounds__(256) void scan1_k(u16* __restrict__ hs,
                                               int* __restrict__ deg32,
                                               int* __restrict__ incl,
                                               int* __restrict__ bsum) {
  __shared__ int sm[256];
  int t = threadIdx.x, i = blockIdx.x * 256 + t;
  int v = 0;
  if (i < NN) {
    int run = 0;
#pragma unroll
    for (int s = 0; s < NSL; ++s) {
      int c = (int)hs[(size_t)s * NN + i];
      hs[(size_t)s * NN + i] = (u16)run;
      run += c;
    }
    v = run + 1;
    deg32[i] = v;
  }
  sm[t] = v; __syncthreads();
  for (int off = 1; off < 256; off <<= 1) {
    int u = (t >= off) ? sm[t - off] : 0;
    __syncthreads();
    sm[t] += u;
    __syncthreads();
  }
  if (i < NN) incl[i] = sm[t];
  if (t == 255) bsum[blockIdx.x] = sm[255];
}

__global__ __launch_bounds__(256) void scan2_k(const int* __restrict__ bsum, int* __restrict__ boff) {
  __shared__ int sm[256];
  int t = threadIdx.x;
  int v = (t < NB1) ? bsum[t] : 0;
  sm[t] = v; __syncthreads();
  for (int off = 1; off < 256; off <<= 1) {
    int u = (t >= off) ? sm[t - off] : 0;
    __syncthreads();
    sm[t] += u;
    __syncthreads();
  }
  if (t < NB1) boff[t] = sm[t] - v;
}

__global__ __launch_bounds__(256) void scan3_k(const int* __restrict__ deg32,
                                               const int* __restrict__ incl,
                                               const int* __restrict__ boff,
                                               int* __restrict__ rowptr,
                                               u16* __restrict__ srcs) {
  int i = blockIdx.x * 256 + threadIdx.x;
  if (i >= NN) return;
  int dg = deg32[i];
  int r = incl[i] - dg + boff[i >> 8];
  rowptr[i] = r;
  srcs[r + dg - 1] = (u16)i;   // self loop in last slot
  if (i == 0) rowptr[NN] = ET;
}

// ==================================================================
// K2: fused [scatter | MFMA gemm1 (h1 + logits via extended N)]
// ==================================================================
__device__ void scatter_role(int sbid, char* smem, const u16* __restrict__ src16,
    const u16* __restrict__ dst16, const int* __restrict__ rowptr,
    const u16* __restrict__ hs, u16* __restrict__ srcs) {
  int* cur = (int*)smem;
  const int oct = sbid & 7;
  const int s   = sbid >> 3;
  const int lo  = oct * OCTW;
  const int tid = threadIdx.x;
  const u16* seed = hs + (size_t)s * NN + lo;
  for (int j = tid; j < OCTW; j += 256)
    cur[j] = rowptr[lo + j] + (int)seed[j];
  __syncthreads();
  const u32x4* dp = (const u32x4*)dst16 + (size_t)s * (SLE / 8);
  const u32x4* sp = (const u32x4*)src16 + (size_t)s * (SLE / 8);
  for (int g = tid; g < SLE / 8; g += 256) {
    u32x4 dv = __builtin_nontemporal_load(&dp[g]);
    u32x4 sv = __builtin_nontemporal_load(&sp[g]);
#pragma unroll
    for (int q = 0; q < 4; ++q) {
      int d0 = (int)(dv[q] & 0xffffu) - lo;
      int d1 = (int)(dv[q] >> 16) - lo;
      if ((unsigned)d0 < OCTW) srcs[atomicAdd(&cur[d0], 1)] = (u16)(sv[q] & 0xffffu);
      if ((unsigned)d1 < OCTW) srcs[atomicAdd(&cur[d1], 1)] = (u16)(sv[q] >> 16);
    }
  }
}

// MFMA gemm1: per block 64 rows; 4 waves x 16 rows; N = 144 (128 h1 + 8 aS + 8 aD)
// Layouts (verified m89): A lane l: row=l&15, k=(l>>4)*8+e; B lane l: col=l&15, same k;
// C/D lane l: col=l&15, row=(l>>4)*4+reg.
__device__ void gemm1_role(int bid, const float* __restrict__ X,
    const __hip_bfloat16* __restrict__ WextT,
    __hip_bfloat16* __restrict__ Yb, float* __restrict__ as1, float* __restrict__ ad1) {
  const int tid = threadIdx.x;
  const int wv = tid >> 6, lane = tid & 63;
  const int row0 = bid * 64 + wv * 16;
  const int mrow = lane & 15;
  const int kq = lane >> 4;
  int garow = row0 + mrow; if (garow > NN - 1) garow = NN - 1;
  const float* xrow = X + (size_t)garow * D1 + kq * 8;
  const char* bbase = (const char*)WextT + (size_t)mrow * 256 + kq * 16;
  f32x4v acc[9] = {};
#pragma unroll
  for (int kt = 0; kt < 4; ++kt) {
    float4 xa = *(const float4*)(xrow + kt * 32);
    float4 xb = *(const float4*)(xrow + kt * 32 + 4);
    bf16x8 af;
    af[0] = (__bf16)xa.x; af[1] = (__bf16)xa.y; af[2] = (__bf16)xa.z; af[3] = (__bf16)xa.w;
    af[4] = (__bf16)xb.x; af[5] = (__bf16)xb.y; af[6] = (__bf16)xb.z; af[7] = (__bf16)xb.w;
#pragma unroll
    for (int nt = 0; nt < 9; ++nt) {
      u32x4 braw = *(const u32x4*)(bbase + (size_t)nt * 4096 + kt * 64);
      bf16x8 bfr = __builtin_bit_cast(bf16x8, braw);
      acc[nt] = __builtin_amdgcn_mfma_f32_16x16x32_bf16(af, bfr, acc[nt], 0, 0, 0);
    }
  }
  const int cl = lane & 15;
#pragma unroll
  for (int reg = 0; reg < 4; ++reg) {
    int gr = row0 + (lane >> 4) * 4 + reg;
    if (gr < NN) {
#pragma unroll
      for (int nt = 0; nt < 8; ++nt)
        Yb[(size_t)gr * D1 + nt * 16 + cl] = __float2bfloat16(acc[nt][reg]);
      float lv = acc[8][reg];
      if (cl < 8) as1[gr * H1 + cl] = lv;
      else        ad1[gr * H1 + (cl - 8)] = lv;
    }
  }
}

__global__ __launch_bounds__(256) void k2_fused(const u16* __restrict__ src16,
    const u16* __restrict__ dst16, const int* __restrict__ rowptr,
    const u16* __restrict__ hs, u16* __restrict__ srcs,
    const float* __restrict__ X, const __hip_bfloat16* __restrict__ WextT,
    __hip_bfloat16* __restrict__ Yb, float* __restrict__ as1, float* __restrict__ ad1) {
  __shared__ __align__(16) char smem[25088];
  const int bid = blockIdx.x;
  if (bid < SCAT_NB) scatter_role(bid, smem, src16, dst16, rowptr, hs, srcs);
  else gemm1_role(bid - SCAT_NB, X, WextT, Yb, as1, ad1);
}

// ==================================================================
// fused layer-1 aggregation: 1 wave per dst, 2 ch per lane; bf16 z out
// ==================================================================
__global__ __launch_bounds__(128) void agg1_k(const int* __restrict__ rowptr,
    const u16* __restrict__ srcs, const u32* __restrict__ h1u,
    const float* __restrict__ as, const float* __restrict__ ad,
    const float* __restrict__ b, u32* __restrict__ zb) {
  __shared__ int ssrc[2][64];
  __shared__ float wl[2][64 * 9];
  __shared__ int lens[2];
  const int w = threadIdx.x >> 6;
  const int lane = threadIdx.x & 63;
  const int d = blockIdx.x * 2 + w;
  const int h = lane >> 3;
  const int beg = rowptr[d], end = rowptr[d + 1];
  if (lane == 0) lens[w] = end - beg;
  __syncthreads();
  const int nb = (max(lens[0], lens[1]) + 63) >> 6;
  const float4 adv0 = *(const float4*)(ad + (size_t)d * H1);
  const float4 adv1 = *(const float4*)(ad + (size_t)d * H1 + 4);
  float aL0 = 0, aL1 = 0, aL2 = 0, aL3 = 0;
  float aH0 = 0, aH1 = 0, aH2 = 0, aH3 = 0;
  float dn0 = 0, dn1 = 0, dn2 = 0, dn3 = 0;
  for (int it = 0; it < nb; ++it) {
    const int base = beg + (it << 6);
    int m = end - base; m = m < 0 ? 0 : (m > 64 ? 64 : m);
    if (lane < m) {
      int s = (int)srcs[base + lane];
      ssrc[w][lane] = s;
      const float4 a0 = *(const float4*)(as + (size_t)s * H1);
      const float4 a1 = *(const float4*)(as + (size_t)s * H1 + 4);
      float* wp = &wl[w][lane * 9];
      float e;
      e = a0.x + adv0.x; e = e > 0.f ? e : 0.2f * e; wp[0] = __expf(e);
      e = a0.y + adv0.y; e = e > 0.f ? e : 0.2f * e; wp[1] = __expf(e);
      e = a0.z + adv0.z; e = e > 0.f ? e : 0.2f * e; wp[2] = __expf(e);
      e = a0.w + adv0.w; e = e > 0.f ? e : 0.2f * e; wp[3] = __expf(e);
      e = a1.x + adv1.x; e = e > 0.f ? e : 0.2f * e; wp[4] = __expf(e);
      e = a1.y + adv1.y; e = e > 0.f ? e : 0.2f * e; wp[5] = __expf(e);
      e = a1.z + adv1.z; e = e > 0.f ? e : 0.2f * e; wp[6] = __expf(e);
      e = a1.w + adv1.w; e = e > 0.f ? e : 0.2f * e; wp[7] = __expf(e);
    }
    __syncthreads();
    int j = 0;
    for (; j + 4 <= m; j += 4) {
      int s0 = ssrc[w][j], s1 = ssrc[w][j + 1], s2 = ssrc[w][j + 2], s3 = ssrc[w][j + 3];
      float w0 = wl[w][(j + 0) * 9 + h], w1 = wl[w][(j + 1) * 9 + h];
      float w2 = wl[w][(j + 2) * 9 + h], w3 = wl[w][(j + 3) * 9 + h];
      u32 v0 = h1u[(size_t)s0 * 64 + lane];
      u32 v1 = h1u[(size_t)s1 * 64 + lane];
      u32 v2 = h1u[(size_t)s2 * 64 + lane];
      u32 v3 = h1u[(size_t)s3 * 64 + lane];
      dn0 += w0; dn1 += w1; dn2 += w2; dn3 += w3;
      aL0 = fmaf(w0, __uint_as_float(v0 << 16), aL0);
      aH0 = fmaf(w0, __uint_as_float(v0 & 0xffff0000u), aH0);
      aL1 = fmaf(w1, __uint_as_float(v1 << 16), aL1);
      aH1 = fmaf(w1, __uint_as_float(v1 & 0xffff0000u), aH1);
      aL2 = fmaf(w2, __uint_as_float(v2 << 16), aL2);
      aH2 = fmaf(w2, __uint_as_float(v2 & 0xffff0000u), aH2);
      aL3 = fmaf(w3, __uint_as_float(v3 << 16), aL3);
      aH3 = fmaf(w3, __uint_as_float(v3 & 0xffff0000u), aH3);
    }
    for (; j < m; ++j) {
      int s0 = ssrc[w][j];
      float w0 = wl[w][j * 9 + h];
      u32 v0 = h1u[(size_t)s0 * 64 + lane];
      dn0 += w0;
      aL0 = fmaf(w0, __uint_as_float(v0 << 16), aL0);
      aH0 = fmaf(w0, __uint_as_float(v0 & 0xffff0000u), aH0);
    }
    __syncthreads();
  }
  float den = (dn0 + dn1) + (dn2 + dn3);
  float aL = (aL0 + aL1) + (aL2 + aL3);
  float aH = (aH0 + aH1) + (aH2 + aH3);
  float inv = 1.f / den;
  float2 bb = *(const float2*)(b + lane * 2);
  float v0 = aL * inv + bb.x;
  float v1 = aH * inv + bb.y;
  v0 = v0 > 0.f ? v0 : __expf(v0) - 1.f;
  v1 = v1 > 0.f ? v1 : __expf(v1) - 1.f;
  __hip_bfloat16 z0 = __float2bfloat16(v0), z1 = __float2bfloat16(v1);
  u32 pu = ((u32)(*(u16*)&z1) << 16) | (u32)(*(u16*)&z0);
  zb[(size_t)d * 64 + lane] = pu;
}

// ==================================================================
// layer 2 GEMM + fused alpha2: bf16 z in, bf16 h2 out
// ==================================================================
__global__ __launch_bounds__(256) void gemm2_k(const u32* __restrict__ Zb,
    const float* __restrict__ W, const float* __restrict__ aS,
    const float* __restrict__ aD, __hip_bfloat16* __restrict__ Yb,
    float* __restrict__ as2, float* __restrict__ ad2) {
  __shared__ float Ws[D1][C2];
  __shared__ float Zs[16][D1 + 4];
  const int tid = threadIdx.x;
  for (int i = tid; i < D1 * C2; i += 256) Ws[i >> 4][i & 15] = W[i];
  const int rb = blockIdx.x * 16;
  {
    int r = tid >> 4, c8 = tid & 15;    // 16 rows x 16 chunks of 8 bf16
    u32x4 raw = *(const u32x4*)(Zb + (size_t)(rb + r) * 64 + c8 * 4);
    float* dst = &Zs[r][c8 * 8];
#pragma unroll
    for (int q = 0; q < 4; ++q) {
      dst[2 * q]     = __uint_as_float(raw[q] << 16);
      dst[2 * q + 1] = __uint_as_float(raw[q] & 0xffff0000u);
    }
  }
  __syncthreads();
  const int r = tid >> 4, c = tid & 15;
  float a0 = 0, a1 = 0, a2 = 0, a3 = 0;
#pragma unroll
  for (int k = 0; k < D1; k += 4) {
    float4 z4 = *(const float4*)&Zs[r][k];
    a0 = fmaf(z4.x, Ws[k][c], a0);
    a1 = fmaf(z4.y, Ws[k + 1][c], a1);
    a2 = fmaf(z4.z, Ws[k + 2][c], a2);
    a3 = fmaf(z4.w, Ws[k + 3][c], a3);
  }
  float acc = (a0 + a1) + (a2 + a3);
  Yb[(size_t)(rb + r) * C2 + c] = __float2bfloat16(acc);
  float ps = acc * aS[c], pd = acc * aD[c];
  ps += __shfl_xor(ps, 1); pd += __shfl_xor(pd, 1);
  ps += __shfl_xor(ps, 2); pd += __shfl_xor(pd, 2);
  ps += __shfl_xor(ps, 4); pd += __shfl_xor(pd, 4);
  ps += __shfl_xor(ps, 8); pd += __shfl_xor(pd, 8);
  if (c == 0) { as2[rb + r] = ps; ad2[rb + r] = pd; }
}

// ==================================================================
// fused layer-2 aggregation: shfl-dedup'd weights (1 exp per edge)
// ==================================================================
__global__ __launch_bounds__(256) void agg2_k(const int* __restrict__ rowptr,
    const u16* __restrict__ srcs, const u32* __restrict__ h2u,
    const float* __restrict__ as, const float* __restrict__ ad,
    const float* __restrict__ b, float* __restrict__ outp) {
  const int wv = threadIdx.x >> 6;
  const int lane = threadIdx.x & 63;
  const int d = blockIdx.x * 4 + wv;
  const int j8 = lane >> 3, cp = lane & 7;
  const int beg = rowptr[d], end = rowptr[d + 1];
  const float adv = ad[d];
  float a0 = 0, a1 = 0, den = 0;
  for (int base = beg; base < end; base += 64) {
    const int m = end - base;
    float wreg = 0.f; int sreg = 0;
    if (lane < m) {
      sreg = (int)srcs[base + lane];
      float e = as[sreg] + adv;
      e = e > 0.f ? e : 0.2f * e;
      wreg = __expf(e);
    }
    const int mm = m < 64 ? m : 64;
    const int rounds = (mm + 7) >> 3;
    for (int r = 0; r < rounds; ++r) {
      int src_lane = r * 8 + j8;
      float wgt = __shfl(wreg, src_lane);
      int s     = __shfl(sreg, src_lane);
      if (wgt > 0.f) {
        u32 v = h2u[(size_t)s * 8 + cp];
        den += wgt;
        a0 = fmaf(wgt, __uint_as_float(v << 16), a0);
        a1 = fmaf(wgt, __uint_as_float(v & 0xffff0000u), a1);
      }
    }
  }
#pragma unroll
  for (int off = 8; off < 64; off <<= 1) {
    a0 += __shfl_xor(a0, off);
    a1 += __shfl_xor(a1, off);
    den += __shfl_xor(den, off);
  }
  if (j8 == 0) {
    float inv = 1.f / den;
    float2 bb = *(const float2*)(b + cp * 2);
    float2 o = {a0 * inv + bb.x, a1 * inv + bb.y};
    *(float2*)(outp + (size_t)d * C2 + cp * 2) = o;
  }
}

extern "C" void kernel_launch(void* const* d_in, const int* in_sizes, int n_in,
                              void* d_out, int out_size, void* d_ws, size_t ws_size,
                              hipStream_t stream) {
  const float* x    = (const float*)d_in[0];
  const int*   ei   = (const int*)d_in[1];
  const float* W1   = (const float*)d_in[2];
  const float* aS1  = (const float*)d_in[3];
  const float* aD1  = (const float*)d_in[4];
  const float* b1   = (const float*)d_in[5];
  const float* W2   = (const float*)d_in[6];
  const float* aS2  = (const float*)d_in[7];
  const float* aD2  = (const float*)d_in[8];
  const float* b2   = (const float*)d_in[9];
  float* outp = (float*)d_out;

  // ---- workspace layout ----
  char* p = (char*)d_ws;
  __hip_bfloat16* h1b = (__hip_bfloat16*)p; p += (size_t)NN * D1 * 2;  // 12.8 MB
  u32* zb   = (u32*)p; p += (size_t)NN * 64 * 4;                        // 12.8 MB (bf16 z)
  float* as1  = (float*)p; p += (size_t)NN * H1 * 4;
  float* ad1  = (float*)p; p += (size_t)NN * H1 * 4;
  __hip_bfloat16* WextT = (__hip_bfloat16*)p; p += (size_t)144 * 128 * 2;  // 36.9 KB
  u16*   hs     = (u16*)p; p += (size_t)NSL * NN * 2;                   // 6.4 MB
  int*   deg32  = (int*)p; p += (size_t)NN * 4;
  int*   incl   = (int*)p; p += (size_t)NN * 4;
  int*   rowptr = (int*)p; p += (size_t)(NN + 1) * 4;
  int*   bsum   = (int*)p; p += 256 * 4;
  int*   boff   = (int*)p; p += 256 * 4;
  u16*   srcs   = (u16*)p; p += (size_t)ET * 2;
  u16*   src16  = (u16*)p; p += (size_t)NE * 2;
  u16*   dst16  = (u16*)p; p += (size_t)NE * 2;
  // layer-2 tensors alias h1b region (dead after agg1)
  __hip_bfloat16* h2b = h1b;
  float* as2 = (float*)(h1b + (size_t)NN * C2);
  float* ad2 = as2 + NN;

  // K1: slice-hist | pack | prep-WextT
  k1_fused<<<HIST_NB + PACK_NB + PREP_NB, 256, 0, stream>>>(
      ei, hs, src16, dst16, W1, aS1, aD1, WextT);

  scan1_k<<<NB1, 256, 0, stream>>>(hs, deg32, incl, bsum);
  scan2_k<<<1, 256, 0, stream>>>(bsum, boff);
  scan3_k<<<NB1, 256, 0, stream>>>(deg32, incl, boff, rowptr, srcs);

  // K2: scatter | MFMA gemm1 (+fused logits)
  k2_fused<<<SCAT_NB + GEMM_NB, 256, 0, stream>>>(
      src16, dst16, rowptr, hs, srcs, x, WextT, h1b, as1, ad1);

  agg1_k <<<NN / 2, 128, 0, stream>>>(rowptr, srcs, (const u32*)h1b, as1, ad1, b1, zb);

  gemm2_k<<<NN / 16, 256, 0, stream>>>(zb, W2, aS2, aD2, h2b, as2, ad2);
  agg2_k <<<NN / 4, 256, 0, stream>>>(rowptr, srcs, (const u32*)h2b, as2, ad2, b2, outp);
}